// Round 1
// 874.482 us; speedup vs baseline: 1.1626x; 1.1626x over previous
//
#include <hip/hip_runtime.h>
#include <stdint.h>

typedef unsigned short u16;
typedef __attribute__((ext_vector_type(8))) __bf16 bf16x8;
typedef __attribute__((ext_vector_type(8))) u16 u16x8;
typedef __attribute__((ext_vector_type(4))) u16 u16x4;
typedef __attribute__((ext_vector_type(4))) float f32x4;

#define LAM 0.95f
#define DISCOUNT (1.0f - 1.0f / 333.0f)

constexpr int Bsz = 1024, Tsz = 16, Dsz = 5120, Hsz = 1024;
constexpr int Msz = Bsz * Tsz;   // 16384
constexpr int Nsz = 2 * Hsz;     // 2048 (net | slow concat on N)
constexpr int ES = 136;          // epilogue LDS tile stride (u16) for legacy kernel

// ---------- helpers ----------
__device__ __forceinline__ u16 f2bf(float x) {
  union { float f; uint32_t u; } un; un.f = x;
  uint32_t u = un.u;
  return (u16)((u + 0x7FFFu + ((u >> 16) & 1u)) >> 16);  // RNE
}
__device__ __forceinline__ void async16(const void* g, void* l) {
  __builtin_amdgcn_global_load_lds(
      (const __attribute__((address_space(1))) uint32_t*)g,
      (__attribute__((address_space(3))) uint32_t*)l, 16, 0, 0);
}

// ---------- prep_all: 4 weight transposes + bias/w3 concat + acc zero, one launch ----------
__global__ __launch_bounds__(256) void prep_all(
    const float* __restrict__ nw1, const float* __restrict__ sw1,
    const float* __restrict__ nw2, const float* __restrict__ sw2,
    const float* nb1, const float* sb1, const float* nb2, const float* sb2,
    const float* nw3, const float* sw3,
    u16* __restrict__ wt1, u16* __restrict__ wt2,
    float* bias1, float* bias2, float* w3cat, float* accs) {
  const int blk = blockIdx.x;
  const int tid = threadIdx.x;
  if (blk < 3072) {
    const float* src; u16* dst; int K, t;
    if (blk < 1280)      { src = nw1; dst = wt1;                        K = Dsz; t = blk; }
    else if (blk < 2560) { src = sw1; dst = wt1 + (size_t)Hsz * Dsz;    K = Dsz; t = blk - 1280; }
    else if (blk < 2816) { src = nw2; dst = wt2;                        K = Hsz; t = blk - 2560; }
    else                 { src = sw2; dst = wt2 + (size_t)Hsz * Hsz;    K = Hsz; t = blk - 2816; }
    const int ktiles = K / 64;
    const int k0 = (t % ktiles) * 64, n0 = (t / ktiles) * 64;
    __shared__ float tile[64][65];
#pragma unroll
    for (int i = 0; i < 4; ++i) {
      int idx = i * 256 + tid, rr = idx >> 4, c4 = (idx & 15) * 4;
      float4 v = *(const float4*)&src[(size_t)(k0 + rr) * Hsz + n0 + c4];
      tile[rr][c4 + 0] = v.x; tile[rr][c4 + 1] = v.y;
      tile[rr][c4 + 2] = v.z; tile[rr][c4 + 3] = v.w;
    }
    __syncthreads();
#pragma unroll
    for (int i = 0; i < 4; ++i) {
      int idx = i * 256 + tid, rr = idx >> 4, c4 = (idx & 15) * 4;
      u16x4 o;
      o[0] = f2bf(tile[c4 + 0][rr]); o[1] = f2bf(tile[c4 + 1][rr]);
      o[2] = f2bf(tile[c4 + 2][rr]); o[3] = f2bf(tile[c4 + 3][rr]);
      *(u16x4*)&dst[(size_t)(n0 + rr) * K + k0 + c4] = o;
    }
  } else {
    int i = (blk - 3072) * 256 + tid;
    if (i < 1024) { bias1[i] = nb1[i]; bias2[i] = nb2[i]; w3cat[i] = nw3[i]; }
    else if (i < 2048) { bias1[i] = sb1[i - 1024]; bias2[i] = sb2[i - 1024]; w3cat[i] = sw3[i - 1024]; }
    for (int j = i; j < 2 * Msz; j += 40 * 256) accs[j] = 0.f;  // accN|accS contiguous
  }
}

// ---------- fp32 -> bf16, 16B loads + 16B stores ----------
__global__ void cvt_f32_to_bf16(const float* __restrict__ src, u16* __restrict__ dst, int n8) {
  int i = blockIdx.x * 256 + threadIdx.x;
  int stride = gridDim.x * 256;
  for (; i < n8; i += stride) {
    float4 v0 = ((const float4*)src)[2 * i];
    float4 v1 = ((const float4*)src)[2 * i + 1];
    u16x8 o;
    o[0] = f2bf(v0.x); o[1] = f2bf(v0.y); o[2] = f2bf(v0.z); o[3] = f2bf(v0.w);
    o[4] = f2bf(v1.x); o[5] = f2bf(v1.y); o[6] = f2bf(v1.z); o[7] = f2bf(v1.w);
    ((u16x8*)dst)[i] = o;
  }
}

// ---------- legacy GEMM1 (128x128, 2-barrier) — small-workspace fallback only ----------
template <bool A_F32>
__global__ __launch_bounds__(256) void gemm1_k(
    const void* __restrict__ Ap, const u16* __restrict__ Bp,
    const float* __restrict__ bias, u16* __restrict__ Out, int K) {
  __shared__ __align__(16) u16 smem[128 * ES];
  u16* ldsA = smem;
  u16* ldsB = smem + 8192;

  const int tid = threadIdx.x;
  const int lane = tid & 63;
  const int wv = tid >> 6;
  const int wm = (wv >> 1) << 6;
  const int wn = (wv & 1) << 6;
  const int lm = lane & 15, lq = lane >> 4, l7 = lane & 7;

  const int blk = blockIdx.x;
  const int xcd = blk & 7;
  const int l = blk >> 3;
  const int quad = l >> 6;
  const int mi = l & 7, ni = (l >> 3) & 7;
  const int mt = xcd * 16 + ((quad & 1) << 3) + mi;
  const int nt = ((quad >> 1) << 3) + ni;
  const int m0 = mt << 7, n0 = nt << 7;

  const u16* bsrc[4];
  const float* asrcf[4];
  const u16* asrcb[4];
  u16* ldsAd[4];
  u16* ldsBd[4];
#pragma unroll
  for (int i = 0; i < 4; ++i) {
    int cid = i * 256 + tid;
    int row = cid >> 3, ch = cid & 7;
    int kp = ch ^ (row & 7);
    bsrc[i] = Bp + (size_t)(n0 + row) * K + kp * 8;
    if (A_F32) asrcf[i] = (const float*)Ap + (size_t)(m0 + row) * K + kp * 8;
    else       asrcb[i] = (const u16*)Ap + (size_t)(m0 + row) * K + kp * 8;
    ldsAd[i] = &ldsA[cid * 8];
    ldsBd[i] = &ldsB[cid * 8];
  }

  int rA[4], rB[4];
#pragma unroll
  for (int t = 0; t < 4; ++t) {
    rA[t] = (wm + t * 16 + lm) * 64;
    rB[t] = (wn + t * 16 + lm) * 64;
  }

  f32x4 acc[4][4];
#pragma unroll
  for (int a = 0; a < 4; ++a)
#pragma unroll
    for (int b = 0; b < 4; ++b) acc[a][b] = f32x4{0.f, 0.f, 0.f, 0.f};

  for (int kt = 0; kt < K; kt += 64) {
#pragma unroll
    for (int i = 0; i < 4; ++i) async16(bsrc[i] + kt, ldsBd[i]);
    if (A_F32) {
      float4 v0[4], v1[4];
#pragma unroll
      for (int i = 0; i < 4; ++i) {
        const float* p = asrcf[i] + kt;
        v0[i] = *(const float4*)p;
        v1[i] = *(const float4*)(p + 4);
      }
#pragma unroll
      for (int i = 0; i < 4; ++i) {
        u16x8 pk;
        pk[0] = f2bf(v0[i].x); pk[1] = f2bf(v0[i].y); pk[2] = f2bf(v0[i].z); pk[3] = f2bf(v0[i].w);
        pk[4] = f2bf(v1[i].x); pk[5] = f2bf(v1[i].y); pk[6] = f2bf(v1[i].z); pk[7] = f2bf(v1[i].w);
        *(u16x8*)ldsAd[i] = pk;
      }
    } else {
#pragma unroll
      for (int i = 0; i < 4; ++i) async16(asrcb[i] + kt, ldsAd[i]);
    }
    __syncthreads();
#pragma unroll
    for (int ks = 0; ks < 2; ++ks) {
      const int ck = ((ks << 2) + lq) ^ l7;
      bf16x8 af[4], bfr[4];
#pragma unroll
      for (int t = 0; t < 4; ++t) af[t] = *(const bf16x8*)&ldsA[rA[t] + ck * 8];
#pragma unroll
      for (int t = 0; t < 4; ++t) bfr[t] = *(const bf16x8*)&ldsB[rB[t] + ck * 8];
#pragma unroll
      for (int a = 0; a < 4; ++a)
#pragma unroll
        for (int b = 0; b < 4; ++b)
          acc[a][b] = __builtin_amdgcn_mfma_f32_16x16x32_bf16(bfr[b], af[a], acc[a][b], 0, 0, 0);
    }
    __syncthreads();
  }

#pragma unroll
  for (int a = 0; a < 4; ++a) {
    int ml = wm + a * 16 + lm;
#pragma unroll
    for (int b = 0; b < 4; ++b) {
      int nb = wn + b * 16 + lq * 4;
      u16x4 pk;
#pragma unroll
      for (int rr = 0; rr < 4; ++rr) {
        float v = acc[a][b][rr] + bias[n0 + nb + rr];
        v = v * (1.0f / (1.0f + __expf(-v)));
        pk[rr] = f2bf(v);
      }
      *(u16x4*)&smem[ml * ES + nb] = pk;
    }
  }
  __syncthreads();
#pragma unroll
  for (int i = 0; i < 8; ++i) {
    int r = i * 16 + (tid >> 4);
    int c = (tid & 15) * 8;
    u16x8 vv = *(const u16x8*)&smem[r * ES + c];
    *(u16x8*)&Out[(size_t)(m0 + r) * Nsz + n0 + c] = vv;
  }
}

// ---------- 8-phase 256x256 GEMM (HK/m201-style schedule, plain HIP) ----------
// 8 waves (2M x 4N), BK=64, double-buffered 128 KiB LDS, counted vmcnt(2) at
// phases 4/8 only (never a full drain in the main loop), raw s_barriers,
// s_setprio(1) around each 16-MFMA cluster. Staging region schedule (region =
// 64 rows x 64 cols = 1 global_load_lds x 16B per thread):
//   slot0 (tile 2it):   Aq0/Aq2/B* last read ph3, Aq1/Aq3 ph4
//   slot1 (tile 2it+1): Aq0/Aq2/B* last read ph7, Aq1/Aq3 ph8
//   stage ph1:B01 ph2:B23 ph3:A13 of slot1-tile | ph4:A02 ph5:B01 ph6:B23
//   ph7:A13 of slot0-next | ph8:A02 of slot1-next  -> every region staged
//   >=1 barrier after its last read; vmcnt(2) leaves exactly the 2 newest in
//   flight, guaranteeing the 8 loads of the slot about to be read have landed.
#define VM(N) asm volatile("s_waitcnt vmcnt(" #N ")" ::: "memory")
#define NOP ((void)0)
#define mfma_(B_, A_, C_) __builtin_amdgcn_mfma_f32_16x16x32_bf16(B_, A_, C_, 0, 0, 0)
#define MFQ(TLO)                                             \
    acc[(TLO)+0][0] = mfma_(bfr[0], a0_, acc[(TLO)+0][0]);   \
    acc[(TLO)+1][0] = mfma_(bfr[0], a1_, acc[(TLO)+1][0]);   \
    acc[(TLO)+2][0] = mfma_(bfr[0], a2_, acc[(TLO)+2][0]);   \
    acc[(TLO)+3][0] = mfma_(bfr[0], a3_, acc[(TLO)+3][0]);   \
    acc[(TLO)+0][1] = mfma_(bfr[1], a0_, acc[(TLO)+0][1]);   \
    acc[(TLO)+1][1] = mfma_(bfr[1], a1_, acc[(TLO)+1][1]);   \
    acc[(TLO)+2][1] = mfma_(bfr[1], a2_, acc[(TLO)+2][1]);   \
    acc[(TLO)+3][1] = mfma_(bfr[1], a3_, acc[(TLO)+3][1]);   \
    acc[(TLO)+0][2] = mfma_(bfr[2], a0_, acc[(TLO)+0][2]);   \
    acc[(TLO)+1][2] = mfma_(bfr[2], a1_, acc[(TLO)+1][2]);   \
    acc[(TLO)+2][2] = mfma_(bfr[2], a2_, acc[(TLO)+2][2]);   \
    acc[(TLO)+3][2] = mfma_(bfr[2], a3_, acc[(TLO)+3][2]);   \
    acc[(TLO)+0][3] = mfma_(bfr[3], a0_, acc[(TLO)+0][3]);   \
    acc[(TLO)+1][3] = mfma_(bfr[3], a1_, acc[(TLO)+1][3]);   \
    acc[(TLO)+2][3] = mfma_(bfr[3], a2_, acc[(TLO)+2][3]);   \
    acc[(TLO)+3][3] = mfma_(bfr[3], a3_, acc[(TLO)+3][3]);

#define PH(S, KS, TLO, RB, STAGES, POST) do {                                  \
    const int ck_ = (((KS) << 2) + lq) ^ l7;                                   \
    const u16* lA_ = &lds[(S)*32768 + (wm + (TLO)*16 + lm)*64 + ck_*8];        \
    bf16x8 a0_ = *(const bf16x8*)(lA_);                                        \
    bf16x8 a1_ = *(const bf16x8*)(lA_ + 1024);                                 \
    bf16x8 a2_ = *(const bf16x8*)(lA_ + 2048);                                 \
    bf16x8 a3_ = *(const bf16x8*)(lA_ + 3072);                                 \
    if (RB) {                                                                  \
      const u16* lB_ = &lds[(S)*32768 + 16384 + (wn + lm)*64 + ck_*8];         \
      bfr[0] = *(const bf16x8*)(lB_);                                          \
      bfr[1] = *(const bf16x8*)(lB_ + 1024);                                   \
      bfr[2] = *(const bf16x8*)(lB_ + 2048);                                   \
      bfr[3] = *(const bf16x8*)(lB_ + 3072);                                   \
    }                                                                          \
    STAGES;                                                                    \
    asm volatile("" ::: "memory");                                             \
    __builtin_amdgcn_s_barrier();                                              \
    asm volatile("s_waitcnt lgkmcnt(0)" ::: "memory");                         \
    __builtin_amdgcn_sched_barrier(0);                                         \
    __builtin_amdgcn_s_setprio(1);                                             \
    MFQ(TLO);                                                                  \
    __builtin_amdgcn_s_setprio(0);                                             \
    __builtin_amdgcn_sched_barrier(0);                                         \
    POST;                                                                      \
    asm volatile("" ::: "memory");                                             \
    __builtin_amdgcn_s_barrier();                                              \
  } while (0)

template <int K, int LDA, bool HEAD>
__global__ __launch_bounds__(512, 2) void gemm8_k(
    const u16* __restrict__ Ap, const u16* __restrict__ Bp,
    const float* __restrict__ bias, u16* __restrict__ Out,
    const float* __restrict__ w3cat, float* __restrict__ accN, float* __restrict__ accS) {
  __shared__ __align__(16) u16 lds[65536];  // [slot][A 16K | B 16K] u16 = 128 KiB

  const int tid = threadIdx.x;
  const int lane = tid & 63;
  const int wv = tid >> 6;
  const int wm = (wv >> 2) << 7;   // 0 / 128
  const int wn = (wv & 3) << 6;    // 0 / 64 / 128 / 192
  const int lm = lane & 15, lq = lane >> 4, l7 = lane & 7;

  // XCD-pinned: blk&7 = XCD; each XCD owns 8 M-tiles x all 8 N-tiles (512 = 8*64, bijective)
  const int blk = blockIdx.x;
  const int xcd = blk & 7, lb = blk >> 3;
  const int mt = xcd * 8 + (lb & 7);
  const int nt = lb >> 3;
  const int m0 = mt << 8, n0 = nt << 8;
  const int a_off = HEAD ? ((n0 >= Hsz) ? Hsz : 0) : 0;

  // staging: region = 64 rows x 8 chunks(16B); thread -> (row sr, chunk sc),
  // global source pre-swizzled so linear LDS dest holds chunk c at slot c^(row&7)
  const int sr = tid >> 3, sc = tid & 7;
  const int skp = sc ^ (sr & 7);
  const uint32_t aoff = (uint32_t)(m0 + sr) * LDA + a_off + skp * 8;
  const uint32_t boff = (uint32_t)(n0 + sr) * K + skp * 8;
  u16* const ldst = &lds[tid << 3];

#define SA(S, Q, T) async16(Ap + aoff + (uint32_t)((Q)*64*LDA) + (uint32_t)((T)*64), ldst + (S)*32768 + (Q)*4096)
#define SB(S, Q, T) async16(Bp + boff + (uint32_t)((Q)*64*K)   + (uint32_t)((T)*64), ldst + (S)*32768 + 16384 + (Q)*4096)

  f32x4 acc[8][4];
#pragma unroll
  for (int a = 0; a < 8; ++a)
#pragma unroll
    for (int b = 0; b < 4; ++b) acc[a][b] = f32x4{0.f, 0.f, 0.f, 0.f};
  bf16x8 bfr[4];

  constexpr int NK = K / 64;
  constexpr int NIT = NK / 2;
  static_assert(NIT >= 2, "need >=2 double-buffer iterations");

  // prologue: tile0 fully into slot0, tile1 Aq0/Aq2 into slot1 (steady-state entry)
  SA(0, 0, 0); SA(0, 1, 0); SA(0, 2, 0); SA(0, 3, 0);
  SB(0, 0, 0); SB(0, 1, 0); SB(0, 2, 0); SB(0, 3, 0);
  SA(1, 0, 1); SA(1, 2, 1);
  VM(2);
  asm volatile("" ::: "memory");
  __builtin_amdgcn_s_barrier();

  int it = 0;
  for (; it < NIT - 1; ++it) {
    const int t1 = 2 * it + 1, t2 = 2 * it + 2, t3 = 2 * it + 3;
    PH(0, 0, 0, 1, SB(1, 0, t1); SB(1, 1, t1), NOP);
    PH(0, 0, 4, 0, SB(1, 2, t1); SB(1, 3, t1), NOP);
    PH(0, 1, 0, 1, SA(1, 1, t1); SA(1, 3, t1), NOP);
    PH(0, 1, 4, 0, SA(0, 0, t2); SA(0, 2, t2), VM(2));
    PH(1, 0, 0, 1, SB(0, 0, t2); SB(0, 1, t2), NOP);
    PH(1, 0, 4, 0, SB(0, 2, t2); SB(0, 3, t2), NOP);
    PH(1, 1, 0, 1, SA(0, 1, t2); SA(0, 3, t2), NOP);
    PH(1, 1, 4, 0, SA(1, 0, t3); SA(1, 2, t3), VM(2));
  }
  {  // final iteration: finish staging tile NK-1, no further prefetch
    const int t1 = 2 * it + 1;
    PH(0, 0, 0, 1, SB(1, 0, t1); SB(1, 1, t1), NOP);
    PH(0, 0, 4, 0, SB(1, 2, t1); SB(1, 3, t1), NOP);
    PH(0, 1, 0, 1, SA(1, 1, t1); SA(1, 3, t1), NOP);
    PH(0, 1, 4, 0, NOP, VM(0));
    PH(1, 0, 0, 1, NOP, NOP);
    PH(1, 0, 4, 0, NOP, NOP);
    PH(1, 1, 0, 1, NOP, NOP);
    PH(1, 1, 4, 0, NOP, NOP);
  }

  if constexpr (!HEAD) {
    // epilogue: bias+silu -> per-wave 128x64 LDS tile (chunk-XOR swizzled) -> 16B stores
#pragma unroll
    for (int t = 0; t < 8; ++t) {
      const int r = t * 16 + lm;
#pragma unroll
      for (int b = 0; b < 4; ++b) {
        const int nb = n0 + wn + b * 16 + lq * 4;
        const f32x4 bv = *(const f32x4*)&bias[nb];
        u16x4 pk;
#pragma unroll
        for (int rr = 0; rr < 4; ++rr) {
          float v = acc[t][b][rr] + bv[rr];
          v = v * (1.0f / (1.0f + __expf(-v)));
          pk[rr] = f2bf(v);
        }
        const int chw = 2 * b + (lq >> 1);
        *(u16x4*)&lds[wv * 8192 + r * 64 + ((chw ^ (r & 7)) << 3) + ((lq & 1) << 2)] = pk;
      }
    }
    asm volatile("s_waitcnt lgkmcnt(0)" ::: "memory");
#pragma unroll
    for (int i = 0; i < 16; ++i) {
      const int r = i * 8 + (lane >> 3);
      const int ch = lane & 7;
      u16x8 vv = *(const u16x8*)&lds[wv * 8192 + r * 64 + ((ch ^ (r & 7)) << 3)];
      *(u16x8*)&Out[(size_t)(m0 + wm + r) * Nsz + n0 + wn + ch * 8] = vv;
    }
  } else {
    // fused w3 head: silu(acc+bias) dot w3, reduce over lq, atomicAdd per row
    float pr[8];
#pragma unroll
    for (int t = 0; t < 8; ++t) pr[t] = 0.f;
#pragma unroll
    for (int t = 0; t < 8; ++t) {
#pragma unroll
      for (int b = 0; b < 4; ++b) {
        const int nb = n0 + wn + b * 16 + lq * 4;
        const f32x4 bv = *(const f32x4*)&bias[nb];
        const f32x4 wv3 = *(const f32x4*)&w3cat[nb];
#pragma unroll
        for (int rr = 0; rr < 4; ++rr) {
          float v = acc[t][b][rr] + bv[rr];
          v = v * (1.0f / (1.0f + __expf(-v)));
          pr[t] += v * wv3[rr];
        }
      }
    }
    float* accp = (n0 < Hsz) ? accN : accS;
#pragma unroll
    for (int t = 0; t < 8; ++t) {
      pr[t] += __shfl_xor(pr[t], 16);
      pr[t] += __shfl_xor(pr[t], 32);
      if (lq == 0) atomicAdd(&accp[m0 + wm + t * 16 + lm], pr[t]);
    }
  }
#undef SA
#undef SB
}

// ---------- finalize + per-batch lambda-return scan ----------
__global__ void finalize_scan(const float* __restrict__ accN, const float* __restrict__ accS,
                              const float* __restrict__ nb3, const float* __restrict__ sb3,
                              const float* __restrict__ voff, const float* __restrict__ vscl,
                              const float* __restrict__ rew, const float* __restrict__ cont,
                              float* __restrict__ o_rew, float* __restrict__ o_ret,
                              float* __restrict__ o_tar, float* __restrict__ o_cri,
                              float* __restrict__ o_slo) {
  __shared__ float star[Tsz], srew[Tsz], scont[Tsz];
  int b = blockIdx.x;
  int t = threadIdx.x;
  if (t < Tsz) {
    int m = b * Tsz + t;
    float c = accN[m] + nb3[0];
    float s = accS[m] + sb3[0];
    float tv = s * vscl[0] + voff[0];
    o_cri[m] = c; o_slo[m] = s; o_tar[m] = tv;
    float rw = rew[m];
    o_rew[m] = rw;
    star[t] = tv; srew[t] = rw; scont[t] = cont[m];
  }
  __syncthreads();
  if (t == 0) {
    float carry = star[Tsz - 1];
    for (int k = Tsz - 2; k >= 0; --k) {
      float d = scont[k + 1] * DISCOUNT;
      carry = srew[k + 1] + (1.0f - LAM) * d * star[k + 1] + d * LAM * carry;
      o_ret[b * (Tsz - 1) + k] = carry;
    }
  }
}

// ---------- workspace layout ----------
constexpr size_t WT1_OFF = 0;
constexpr size_t WT1_BYTES = (size_t)Nsz * Dsz * 2;
constexpr size_t WT2_OFF = WT1_OFF + WT1_BYTES;
constexpr size_t WT2_BYTES = (size_t)Nsz * Hsz * 2;
constexpr size_t B1_OFF = WT2_OFF + WT2_BYTES;
constexpr size_t B2_OFF = B1_OFF + 8192;
constexpr size_t W3_OFF = B2_OFF + 8192;
constexpr size_t ACCN_OFF = W3_OFF + 8192;
constexpr size_t ACCS_OFF = ACCN_OFF + (size_t)Msz * 4;
constexpr size_t H1_OFF = ACCS_OFF + (size_t)Msz * 4;
constexpr size_t H_BYTES = (size_t)Msz * Nsz * 2;
constexpr size_t FEATB_OFF = H1_OFF + H_BYTES;
constexpr size_t FEATB_BYTES = (size_t)Msz * Dsz * 2;
constexpr size_t NEED_BIG = FEATB_OFF + FEATB_BYTES;

extern "C" void kernel_launch(void* const* d_in, const int* in_sizes, int n_in,
                              void* d_out, int out_size, void* d_ws, size_t ws_size,
                              hipStream_t stream) {
  const float* feat = (const float*)d_in[0];
  const float* rew  = (const float*)d_in[1];
  const float* cont = (const float*)d_in[2];
  const float* nw1  = (const float*)d_in[3];
  const float* nb1  = (const float*)d_in[4];
  const float* nw2  = (const float*)d_in[5];
  const float* nb2  = (const float*)d_in[6];
  const float* nw3  = (const float*)d_in[7];
  const float* nb3  = (const float*)d_in[8];
  const float* sw1  = (const float*)d_in[9];
  const float* sb1  = (const float*)d_in[10];
  const float* sw2  = (const float*)d_in[11];
  const float* sb2  = (const float*)d_in[12];
  const float* sw3  = (const float*)d_in[13];
  const float* sb3  = (const float*)d_in[14];
  const float* voff = (const float*)d_in[15];
  const float* vscl = (const float*)d_in[16];

  char* ws = (char*)d_ws;
  u16* wt1 = (u16*)(ws + WT1_OFF);
  u16* wt2 = (u16*)(ws + WT2_OFF);
  float* bias1 = (float*)(ws + B1_OFF);
  float* bias2 = (float*)(ws + B2_OFF);
  float* w3cat = (float*)(ws + W3_OFF);
  float* accN = (float*)(ws + ACCN_OFF);
  float* accS = (float*)(ws + ACCS_OFF);
  u16* h1 = (u16*)(ws + H1_OFF);
  u16* featb = (u16*)(ws + FEATB_OFF);
  const bool big = ws_size >= NEED_BIG;

  float* out = (float*)d_out;
  float* o_rew = out;
  float* o_ret = out + 16384;
  float* o_tar = out + 31744;
  float* o_cri = out + 48128;
  float* o_slo = out + 64512;

  prep_all<<<3112, 256, 0, stream>>>(nw1, sw1, nw2, sw2, nb1, sb1, nb2, sb2, nw3, sw3,
                                     wt1, wt2, bias1, bias2, w3cat, accN);

  const int g8 = (Msz / 256) * (Nsz / 256);  // 512
  if (big) {
    cvt_f32_to_bf16<<<4096, 256, 0, stream>>>(feat, featb, Msz * Dsz / 8);
    gemm8_k<Dsz, Dsz, false><<<g8, 512, 0, stream>>>(featb, wt1, bias1, h1,
                                                     nullptr, nullptr, nullptr);
  } else {
    gemm1_k<true><<<(Msz / 128) * (Nsz / 128), 256, 0, stream>>>(feat, wt1, bias1, h1, Dsz);
  }
  gemm8_k<Hsz, Nsz, true><<<g8, 512, 0, stream>>>(h1, wt2, bias2, nullptr,
                                                  w3cat, accN, accS);
  finalize_scan<<<Bsz, 64, 0, stream>>>(accN, accS, nb3, sb3, voff, vscl, rew, cont,
                                        o_rew, o_ret, o_tar, o_cri, o_slo);
}

// Round 2
// 864.780 us; speedup vs baseline: 1.1756x; 1.0112x over previous
//
#include <hip/hip_runtime.h>
#include <stdint.h>

typedef unsigned short u16;
typedef __attribute__((ext_vector_type(8))) __bf16 bf16x8;
typedef __attribute__((ext_vector_type(8))) u16 u16x8;
typedef __attribute__((ext_vector_type(4))) u16 u16x4;
typedef __attribute__((ext_vector_type(4))) float f32x4;

#define LAM 0.95f
#define DISCOUNT (1.0f - 1.0f / 333.0f)

constexpr int Bsz = 1024, Tsz = 16, Dsz = 5120, Hsz = 1024;
constexpr int Msz = Bsz * Tsz;   // 16384
constexpr int Nsz = 2 * Hsz;     // 2048 (net | slow concat on N)
constexpr int ES = 136;          // epilogue LDS tile stride (u16) for legacy kernel

// ---------- helpers ----------
__device__ __forceinline__ u16 f2bf(float x) {
  union { float f; uint32_t u; } un; un.f = x;
  uint32_t u = un.u;
  return (u16)((u + 0x7FFFu + ((u >> 16) & 1u)) >> 16);  // RNE
}
__device__ __forceinline__ void async16(const void* g, void* l) {
  __builtin_amdgcn_global_load_lds(
      (const __attribute__((address_space(1))) uint32_t*)g,
      (__attribute__((address_space(3))) uint32_t*)l, 16, 0, 0);
}

// ---------- prep_all: weight transposes + bias/w3 concat + acc zero + feat cvt ----------
// blocks 0..3071: transposes; 3072..3111: misc; 3112+: f32->bf16 feat conversion
__global__ __launch_bounds__(256) void prep_all(
    const float* __restrict__ nw1, const float* __restrict__ sw1,
    const float* __restrict__ nw2, const float* __restrict__ sw2,
    const float* nb1, const float* sb1, const float* nb2, const float* sb2,
    const float* nw3, const float* sw3,
    u16* __restrict__ wt1, u16* __restrict__ wt2,
    float* bias1, float* bias2, float* w3cat, float* accs,
    const float* __restrict__ feat, u16* __restrict__ featb, int n8) {
  const int blk = blockIdx.x;
  const int tid = threadIdx.x;
  if (blk < 3072) {
    const float* src; u16* dst; int K, t;
    if (blk < 1280)      { src = nw1; dst = wt1;                        K = Dsz; t = blk; }
    else if (blk < 2560) { src = sw1; dst = wt1 + (size_t)Hsz * Dsz;    K = Dsz; t = blk - 1280; }
    else if (blk < 2816) { src = nw2; dst = wt2;                        K = Hsz; t = blk - 2560; }
    else                 { src = sw2; dst = wt2 + (size_t)Hsz * Hsz;    K = Hsz; t = blk - 2816; }
    const int ktiles = K / 64;
    const int k0 = (t % ktiles) * 64, n0 = (t / ktiles) * 64;
    __shared__ float tile[64][65];
#pragma unroll
    for (int i = 0; i < 4; ++i) {
      int idx = i * 256 + tid, rr = idx >> 4, c4 = (idx & 15) * 4;
      float4 v = *(const float4*)&src[(size_t)(k0 + rr) * Hsz + n0 + c4];
      tile[rr][c4 + 0] = v.x; tile[rr][c4 + 1] = v.y;
      tile[rr][c4 + 2] = v.z; tile[rr][c4 + 3] = v.w;
    }
    __syncthreads();
#pragma unroll
    for (int i = 0; i < 4; ++i) {
      int idx = i * 256 + tid, rr = idx >> 4, c4 = (idx & 15) * 4;
      u16x4 o;
      o[0] = f2bf(tile[c4 + 0][rr]); o[1] = f2bf(tile[c4 + 1][rr]);
      o[2] = f2bf(tile[c4 + 2][rr]); o[3] = f2bf(tile[c4 + 3][rr]);
      *(u16x4*)&dst[(size_t)(n0 + rr) * K + k0 + c4] = o;
    }
  } else if (blk < 3112) {
    int i = (blk - 3072) * 256 + tid;
    if (i < 1024) { bias1[i] = nb1[i]; bias2[i] = nb2[i]; w3cat[i] = nw3[i]; }
    else if (i < 2048) { bias1[i] = sb1[i - 1024]; bias2[i] = sb2[i - 1024]; w3cat[i] = sw3[i - 1024]; }
    for (int j = i; j < 2 * Msz; j += 40 * 256) accs[j] = 0.f;  // accN|accS contiguous
  } else {
    int i = (blk - 3112) * 256 + tid;
    int stride = (gridDim.x - 3112) * 256;
    for (; i < n8; i += stride) {
      float4 v0 = ((const float4*)feat)[2 * i];
      float4 v1 = ((const float4*)feat)[2 * i + 1];
      u16x8 o;
      o[0] = f2bf(v0.x); o[1] = f2bf(v0.y); o[2] = f2bf(v0.z); o[3] = f2bf(v0.w);
      o[4] = f2bf(v1.x); o[5] = f2bf(v1.y); o[6] = f2bf(v1.z); o[7] = f2bf(v1.w);
      ((u16x8*)featb)[i] = o;
    }
  }
}

// ---------- legacy GEMM1 (128x128, 2-barrier) — small-workspace fallback only ----------
template <bool A_F32>
__global__ __launch_bounds__(256) void gemm1_k(
    const void* __restrict__ Ap, const u16* __restrict__ Bp,
    const float* __restrict__ bias, u16* __restrict__ Out, int K) {
  __shared__ __align__(16) u16 smem[128 * ES];
  u16* ldsA = smem;
  u16* ldsB = smem + 8192;

  const int tid = threadIdx.x;
  const int lane = tid & 63;
  const int wv = tid >> 6;
  const int wm = (wv >> 1) << 6;
  const int wn = (wv & 1) << 6;
  const int lm = lane & 15, lq = lane >> 4, l7 = lane & 7;

  const int blk = blockIdx.x;
  const int xcd = blk & 7;
  const int l = blk >> 3;
  const int quad = l >> 6;
  const int mi = l & 7, ni = (l >> 3) & 7;
  const int mt = xcd * 16 + ((quad & 1) << 3) + mi;
  const int nt = ((quad >> 1) << 3) + ni;
  const int m0 = mt << 7, n0 = nt << 7;

  const u16* bsrc[4];
  const float* asrcf[4];
  const u16* asrcb[4];
  u16* ldsAd[4];
  u16* ldsBd[4];
#pragma unroll
  for (int i = 0; i < 4; ++i) {
    int cid = i * 256 + tid;
    int row = cid >> 3, ch = cid & 7;
    int kp = ch ^ (row & 7);
    bsrc[i] = Bp + (size_t)(n0 + row) * K + kp * 8;
    if (A_F32) asrcf[i] = (const float*)Ap + (size_t)(m0 + row) * K + kp * 8;
    else       asrcb[i] = (const u16*)Ap + (size_t)(m0 + row) * K + kp * 8;
    ldsAd[i] = &ldsA[cid * 8];
    ldsBd[i] = &ldsB[cid * 8];
  }

  int rA[4], rB[4];
#pragma unroll
  for (int t = 0; t < 4; ++t) {
    rA[t] = (wm + t * 16 + lm) * 64;
    rB[t] = (wn + t * 16 + lm) * 64;
  }

  f32x4 acc[4][4];
#pragma unroll
  for (int a = 0; a < 4; ++a)
#pragma unroll
    for (int b = 0; b < 4; ++b) acc[a][b] = f32x4{0.f, 0.f, 0.f, 0.f};

  for (int kt = 0; kt < K; kt += 64) {
#pragma unroll
    for (int i = 0; i < 4; ++i) async16(bsrc[i] + kt, ldsBd[i]);
    if (A_F32) {
      float4 v0[4], v1[4];
#pragma unroll
      for (int i = 0; i < 4; ++i) {
        const float* p = asrcf[i] + kt;
        v0[i] = *(const float4*)p;
        v1[i] = *(const float4*)(p + 4);
      }
#pragma unroll
      for (int i = 0; i < 4; ++i) {
        u16x8 pk;
        pk[0] = f2bf(v0[i].x); pk[1] = f2bf(v0[i].y); pk[2] = f2bf(v0[i].z); pk[3] = f2bf(v0[i].w);
        pk[4] = f2bf(v1[i].x); pk[5] = f2bf(v1[i].y); pk[6] = f2bf(v1[i].z); pk[7] = f2bf(v1[i].w);
        *(u16x8*)ldsAd[i] = pk;
      }
    } else {
#pragma unroll
      for (int i = 0; i < 4; ++i) async16(asrcb[i] + kt, ldsAd[i]);
    }
    __syncthreads();
#pragma unroll
    for (int ks = 0; ks < 2; ++ks) {
      const int ck = ((ks << 2) + lq) ^ l7;
      bf16x8 af[4], bfr[4];
#pragma unroll
      for (int t = 0; t < 4; ++t) af[t] = *(const bf16x8*)&ldsA[rA[t] + ck * 8];
#pragma unroll
      for (int t = 0; t < 4; ++t) bfr[t] = *(const bf16x8*)&ldsB[rB[t] + ck * 8];
#pragma unroll
      for (int a = 0; a < 4; ++a)
#pragma unroll
        for (int b = 0; b < 4; ++b)
          acc[a][b] = __builtin_amdgcn_mfma_f32_16x16x32_bf16(bfr[b], af[a], acc[a][b], 0, 0, 0);
    }
    __syncthreads();
  }

#pragma unroll
  for (int a = 0; a < 4; ++a) {
    int ml = wm + a * 16 + lm;
#pragma unroll
    for (int b = 0; b < 4; ++b) {
      int nb = wn + b * 16 + lq * 4;
      u16x4 pk;
#pragma unroll
      for (int rr = 0; rr < 4; ++rr) {
        float v = acc[a][b][rr] + bias[n0 + nb + rr];
        v = v * (1.0f / (1.0f + __expf(-v)));
        pk[rr] = f2bf(v);
      }
      *(u16x4*)&smem[ml * ES + nb] = pk;
    }
  }
  __syncthreads();
#pragma unroll
  for (int i = 0; i < 8; ++i) {
    int r = i * 16 + (tid >> 4);
    int c = (tid & 15) * 8;
    u16x8 vv = *(const u16x8*)&smem[r * ES + c];
    *(u16x8*)&Out[(size_t)(m0 + r) * Nsz + n0 + c] = vv;
  }
}

// ---------- 8-phase 256x256 GEMM, deep-prefetch schedule ----------
// 8 waves (2M x 4N), BK=64, double-buffered 128 KiB LDS.
// In-tile phase order: (ks0,TLO0),(ks1,TLO0),(ks0,TLO4),(ks1,TLO4) — both B chunk
// sets held in regs (bfr0/bfr1) so A02/B free after ph2(ph6), A13 after ph4(ph8).
// Steady-state staging (region = 64rows x 64cols = 1 gload_lds x 16B/thread):
//   ph1: A13(s1, cur t1)          [read ph7/ph8      -> enforce VM@ph6, dist 5]
//   ph3: A02+B01(s0, next t2)     [read next ph1-4   -> enforce VM@ph8, dist 5]
//   ph4: B23(s0, t2)              [                  -> VM@ph8, dist 4]
//   ph5: A13(s0, t2)              [read next ph3/4   -> VM@ph8, dist 3]
//   ph7: A02+B01(s1, next t3)     [read next ph5-8   -> VM@next ph4, dist 5]
//   ph8: B23(s1, t3)              [                  -> VM@next ph4, dist 4]
// VM(8)@ph4, VM(8)@ph6, VM(6)@ph8; invariant: 6 loads in flight entering ph1.
// Min issue->enforce distance = 3 phases (~450cy) vs 1 phase in the old order.
#define VM(N) asm volatile("s_waitcnt vmcnt(" #N ")" ::: "memory")
#define NOP ((void)0)
#define mfma_(B_, A_, C_) __builtin_amdgcn_mfma_f32_16x16x32_bf16(B_, A_, C_, 0, 0, 0)
#define MFQ(TLO, BF)                                         \
    acc[(TLO)+0][0] = mfma_(BF[0], a0_, acc[(TLO)+0][0]);    \
    acc[(TLO)+1][0] = mfma_(BF[0], a1_, acc[(TLO)+1][0]);    \
    acc[(TLO)+2][0] = mfma_(BF[0], a2_, acc[(TLO)+2][0]);    \
    acc[(TLO)+3][0] = mfma_(BF[0], a3_, acc[(TLO)+3][0]);    \
    acc[(TLO)+0][1] = mfma_(BF[1], a0_, acc[(TLO)+0][1]);    \
    acc[(TLO)+1][1] = mfma_(BF[1], a1_, acc[(TLO)+1][1]);    \
    acc[(TLO)+2][1] = mfma_(BF[1], a2_, acc[(TLO)+2][1]);    \
    acc[(TLO)+3][1] = mfma_(BF[1], a3_, acc[(TLO)+3][1]);    \
    acc[(TLO)+0][2] = mfma_(BF[2], a0_, acc[(TLO)+0][2]);    \
    acc[(TLO)+1][2] = mfma_(BF[2], a1_, acc[(TLO)+1][2]);    \
    acc[(TLO)+2][2] = mfma_(BF[2], a2_, acc[(TLO)+2][2]);    \
    acc[(TLO)+3][2] = mfma_(BF[2], a3_, acc[(TLO)+3][2]);    \
    acc[(TLO)+0][3] = mfma_(BF[3], a0_, acc[(TLO)+0][3]);    \
    acc[(TLO)+1][3] = mfma_(BF[3], a1_, acc[(TLO)+1][3]);    \
    acc[(TLO)+2][3] = mfma_(BF[3], a2_, acc[(TLO)+2][3]);    \
    acc[(TLO)+3][3] = mfma_(BF[3], a3_, acc[(TLO)+3][3]);

#define PH(S, KS, TLO, BF, RB, STAGES, POST) do {                              \
    const int ck_ = (((KS) << 2) + lq) ^ l7;                                   \
    const u16* lA_ = &lds[(S)*32768 + (wm + (TLO)*16 + lm)*64 + ck_*8];        \
    bf16x8 a0_ = *(const bf16x8*)(lA_);                                        \
    bf16x8 a1_ = *(const bf16x8*)(lA_ + 1024);                                 \
    bf16x8 a2_ = *(const bf16x8*)(lA_ + 2048);                                 \
    bf16x8 a3_ = *(const bf16x8*)(lA_ + 3072);                                 \
    if (RB) {                                                                  \
      const u16* lB_ = &lds[(S)*32768 + 16384 + (wn + lm)*64 + ck_*8];         \
      BF[0] = *(const bf16x8*)(lB_);                                           \
      BF[1] = *(const bf16x8*)(lB_ + 1024);                                    \
      BF[2] = *(const bf16x8*)(lB_ + 2048);                                    \
      BF[3] = *(const bf16x8*)(lB_ + 3072);                                    \
    }                                                                          \
    STAGES;                                                                    \
    asm volatile("" ::: "memory");                                             \
    __builtin_amdgcn_s_barrier();                                              \
    asm volatile("s_waitcnt lgkmcnt(0)" ::: "memory");                         \
    __builtin_amdgcn_sched_barrier(0);                                         \
    __builtin_amdgcn_s_setprio(1);                                             \
    MFQ(TLO, BF);                                                              \
    __builtin_amdgcn_s_setprio(0);                                             \
    __builtin_amdgcn_sched_barrier(0);                                         \
    POST;                                                                      \
    asm volatile("" ::: "memory");                                             \
    __builtin_amdgcn_s_barrier();                                              \
  } while (0)

template <int K, int LDA, bool HEAD>
__global__ __launch_bounds__(512, 2) void gemm8_k(
    const u16* __restrict__ Ap, const u16* __restrict__ Bp,
    const float* __restrict__ bias, u16* __restrict__ Out,
    const float* __restrict__ w3cat, float* __restrict__ accN, float* __restrict__ accS) {
  __shared__ __align__(16) u16 lds[65536];  // [slot][A 16K | B 16K] u16 = 128 KiB

  const int tid = threadIdx.x;
  const int lane = tid & 63;
  const int wv = tid >> 6;
  const int wm = (wv >> 2) << 7;   // 0 / 128
  const int wn = (wv & 3) << 6;    // 0 / 64 / 128 / 192
  const int lm = lane & 15, lq = lane >> 4, l7 = lane & 7;

  // XCD-pinned: blk&7 = XCD; each XCD owns 8 M-tiles x all 8 N-tiles (512 = 8*64, bijective)
  const int blk = blockIdx.x;
  const int xcd = blk & 7, lb = blk >> 3;
  const int mt = xcd * 8 + (lb & 7);
  const int nt = lb >> 3;
  const int m0 = mt << 8, n0 = nt << 8;
  const int a_off = HEAD ? ((n0 >= Hsz) ? Hsz : 0) : 0;

  // staging: region = 64 rows x 8 chunks(16B); thread -> (row sr, chunk sc),
  // global source pre-swizzled so linear LDS dest holds chunk c at slot c^(row&7)
  const int sr = tid >> 3, sc = tid & 7;
  const int skp = sc ^ (sr & 7);
  const uint32_t aoff = (uint32_t)(m0 + sr) * LDA + a_off + skp * 8;
  const uint32_t boff = (uint32_t)(n0 + sr) * K + skp * 8;
  u16* const ldst = &lds[tid << 3];

#define SA(S, Q, T) async16(Ap + aoff + (uint32_t)((Q)*64*LDA) + (uint32_t)((T)*64), ldst + (S)*32768 + (Q)*4096)
#define SB(S, Q, T) async16(Bp + boff + (uint32_t)((Q)*64*K)   + (uint32_t)((T)*64), ldst + (S)*32768 + 16384 + (Q)*4096)

  f32x4 acc[8][4];
#pragma unroll
  for (int a = 0; a < 8; ++a)
#pragma unroll
    for (int b = 0; b < 4; ++b) acc[a][b] = f32x4{0.f, 0.f, 0.f, 0.f};
  bf16x8 bfr0[4], bfr1[4];

  constexpr int NK = K / 64;
  constexpr int NIT = NK / 2;
  static_assert(NK % 2 == 0 && NIT >= 2, "need >=2 double-buffer iterations");

  // prologue: tile0 fully into slot0; tile1 A02+B fully into slot1 (A13(s1,t1) staged at ph1)
  SA(0, 0, 0); SA(0, 1, 0); SA(0, 2, 0); SA(0, 3, 0);
  SB(0, 0, 0); SB(0, 1, 0); SB(0, 2, 0); SB(0, 3, 0);
  SA(1, 0, 1); SA(1, 2, 1);
  SB(1, 0, 1); SB(1, 1, 1); SB(1, 2, 1); SB(1, 3, 1);
  VM(6);
  asm volatile("" ::: "memory");
  __builtin_amdgcn_s_barrier();

  int it = 0;
  for (; it < NIT - 1; ++it) {
    const int t1 = 2 * it + 1, t2 = 2 * it + 2, t3 = 2 * it + 3;
    PH(0, 0, 0, bfr0, 1, SA(1, 1, t1); SA(1, 3, t1), NOP);
    PH(0, 1, 0, bfr1, 1, NOP, NOP);
    PH(0, 0, 4, bfr0, 0, SA(0, 0, t2); SA(0, 2, t2); SB(0, 0, t2); SB(0, 1, t2), NOP);
    PH(0, 1, 4, bfr1, 0, SB(0, 2, t2); SB(0, 3, t2), VM(8));
    PH(1, 0, 0, bfr0, 1, SA(0, 1, t2); SA(0, 3, t2), NOP);
    PH(1, 1, 0, bfr1, 1, NOP, VM(8));
    PH(1, 0, 4, bfr0, 0, SA(1, 0, t3); SA(1, 2, t3); SB(1, 0, t3); SB(1, 1, t3), NOP);
    PH(1, 1, 4, bfr1, 0, SB(1, 2, t3); SB(1, 3, t3), VM(6));
  }
  {  // final iteration: finish staging tile NK-1 (A13 at ph1), drain VMs
    const int t1 = 2 * it + 1;
    PH(0, 0, 0, bfr0, 1, SA(1, 1, t1); SA(1, 3, t1), NOP);
    PH(0, 1, 0, bfr1, 1, NOP, NOP);
    PH(0, 0, 4, bfr0, 0, NOP, NOP);
    PH(0, 1, 4, bfr1, 0, NOP, VM(2));
    PH(1, 0, 0, bfr0, 1, NOP, NOP);
    PH(1, 1, 0, bfr1, 1, NOP, VM(0));
    PH(1, 0, 4, bfr0, 0, NOP, NOP);
    PH(1, 1, 4, bfr1, 0, NOP, NOP);
  }

  if constexpr (!HEAD) {
    // epilogue: bias+silu -> per-wave 128x64 LDS tile (chunk-XOR swizzled) -> 16B stores
#pragma unroll
    for (int t = 0; t < 8; ++t) {
      const int r = t * 16 + lm;
#pragma unroll
      for (int b = 0; b < 4; ++b) {
        const int nb = n0 + wn + b * 16 + lq * 4;
        const f32x4 bv = *(const f32x4*)&bias[nb];
        u16x4 pk;
#pragma unroll
        for (int rr = 0; rr < 4; ++rr) {
          float v = acc[t][b][rr] + bv[rr];
          v = v * (1.0f / (1.0f + __expf(-v)));
          pk[rr] = f2bf(v);
        }
        const int chw = 2 * b + (lq >> 1);
        *(u16x4*)&lds[wv * 8192 + r * 64 + ((chw ^ (r & 7)) << 3) + ((lq & 1) << 2)] = pk;
      }
    }
    asm volatile("s_waitcnt lgkmcnt(0)" ::: "memory");
#pragma unroll
    for (int i = 0; i < 16; ++i) {
      const int r = i * 8 + (lane >> 3);
      const int ch = lane & 7;
      u16x8 vv = *(const u16x8*)&lds[wv * 8192 + r * 64 + ((ch ^ (r & 7)) << 3)];
      *(u16x8*)&Out[(size_t)(m0 + wm + r) * Nsz + n0 + wn + ch * 8] = vv;
    }
  } else {
    // fused w3 head: silu(acc+bias) dot w3, reduce over lq, atomicAdd per row
    float pr[8];
#pragma unroll
    for (int t = 0; t < 8; ++t) pr[t] = 0.f;
#pragma unroll
    for (int t = 0; t < 8; ++t) {
#pragma unroll
      for (int b = 0; b < 4; ++b) {
        const int nb = n0 + wn + b * 16 + lq * 4;
        const f32x4 bv = *(const f32x4*)&bias[nb];
        const f32x4 wv3 = *(const f32x4*)&w3cat[nb];
#pragma unroll
        for (int rr = 0; rr < 4; ++rr) {
          float v = acc[t][b][rr] + bv[rr];
          v = v * (1.0f / (1.0f + __expf(-v)));
          pr[t] += v * wv3[rr];
        }
      }
    }
    float* accp = (n0 < Hsz) ? accN : accS;
#pragma unroll
    for (int t = 0; t < 8; ++t) {
      pr[t] += __shfl_xor(pr[t], 16);
      pr[t] += __shfl_xor(pr[t], 32);
      if (lq == 0) atomicAdd(&accp[m0 + wm + t * 16 + lm], pr[t]);
    }
  }
#undef SA
#undef SB
}

// ---------- finalize + per-batch lambda-return scan ----------
__global__ void finalize_scan(const float* __restrict__ accN, const float* __restrict__ accS,
                              const float* __restrict__ nb3, const float* __restrict__ sb3,
                              const float* __restrict__ voff, const float* __restrict__ vscl,
                              const float* __restrict__ rew, const float* __restrict__ cont,
                              float* __restrict__ o_rew, float* __restrict__ o_ret,
                              float* __restrict__ o_tar, float* __restrict__ o_cri,
                              float* __restrict__ o_slo) {
  __shared__ float star[Tsz], srew[Tsz], scont[Tsz];
  int b = blockIdx.x;
  int t = threadIdx.x;
  if (t < Tsz) {
    int m = b * Tsz + t;
    float c = accN[m] + nb3[0];
    float s = accS[m] + sb3[0];
    float tv = s * vscl[0] + voff[0];
    o_cri[m] = c; o_slo[m] = s; o_tar[m] = tv;
    float rw = rew[m];
    o_rew[m] = rw;
    star[t] = tv; srew[t] = rw; scont[t] = cont[m];
  }
  __syncthreads();
  if (t == 0) {
    float carry = star[Tsz - 1];
    for (int k = Tsz - 2; k >= 0; --k) {
      float d = scont[k + 1] * DISCOUNT;
      carry = srew[k + 1] + (1.0f - LAM) * d * star[k + 1] + d * LAM * carry;
      o_ret[b * (Tsz - 1) + k] = carry;
    }
  }
}

// ---------- workspace layout ----------
constexpr size_t WT1_OFF = 0;
constexpr size_t WT1_BYTES = (size_t)Nsz * Dsz * 2;
constexpr size_t WT2_OFF = WT1_OFF + WT1_BYTES;
constexpr size_t WT2_BYTES = (size_t)Nsz * Hsz * 2;
constexpr size_t B1_OFF = WT2_OFF + WT2_BYTES;
constexpr size_t B2_OFF = B1_OFF + 8192;
constexpr size_t W3_OFF = B2_OFF + 8192;
constexpr size_t ACCN_OFF = W3_OFF + 8192;
constexpr size_t ACCS_OFF = ACCN_OFF + (size_t)Msz * 4;
constexpr size_t H1_OFF = ACCS_OFF + (size_t)Msz * 4;
constexpr size_t H_BYTES = (size_t)Msz * Nsz * 2;
constexpr size_t FEATB_OFF = H1_OFF + H_BYTES;
constexpr size_t FEATB_BYTES = (size_t)Msz * Dsz * 2;
constexpr size_t NEED_BIG = FEATB_OFF + FEATB_BYTES;

extern "C" void kernel_launch(void* const* d_in, const int* in_sizes, int n_in,
                              void* d_out, int out_size, void* d_ws, size_t ws_size,
                              hipStream_t stream) {
  const float* feat = (const float*)d_in[0];
  const float* rew  = (const float*)d_in[1];
  const float* cont = (const float*)d_in[2];
  const float* nw1  = (const float*)d_in[3];
  const float* nb1  = (const float*)d_in[4];
  const float* nw2  = (const float*)d_in[5];
  const float* nb2  = (const float*)d_in[6];
  const float* nw3  = (const float*)d_in[7];
  const float* nb3  = (const float*)d_in[8];
  const float* sw1  = (const float*)d_in[9];
  const float* sb1  = (const float*)d_in[10];
  const float* sw2  = (const float*)d_in[11];
  const float* sb2  = (const float*)d_in[12];
  const float* sw3  = (const float*)d_in[13];
  const float* sb3  = (const float*)d_in[14];
  const float* voff = (const float*)d_in[15];
  const float* vscl = (const float*)d_in[16];

  char* ws = (char*)d_ws;
  u16* wt1 = (u16*)(ws + WT1_OFF);
  u16* wt2 = (u16*)(ws + WT2_OFF);
  float* bias1 = (float*)(ws + B1_OFF);
  float* bias2 = (float*)(ws + B2_OFF);
  float* w3cat = (float*)(ws + W3_OFF);
  float* accN = (float*)(ws + ACCN_OFF);
  float* accS = (float*)(ws + ACCS_OFF);
  u16* h1 = (u16*)(ws + H1_OFF);
  u16* featb = (u16*)(ws + FEATB_OFF);
  const bool big = ws_size >= NEED_BIG;

  float* out = (float*)d_out;
  float* o_rew = out;
  float* o_ret = out + 16384;
  float* o_tar = out + 31744;
  float* o_cri = out + 48128;
  float* o_slo = out + 64512;

  const int g8 = (Msz / 256) * (Nsz / 256);  // 512
  if (big) {
    prep_all<<<3112 + 4096, 256, 0, stream>>>(nw1, sw1, nw2, sw2, nb1, sb1, nb2, sb2,
                                              nw3, sw3, wt1, wt2, bias1, bias2, w3cat,
                                              accN, feat, featb, Msz * Dsz / 8);
    gemm8_k<Dsz, Dsz, false><<<g8, 512, 0, stream>>>(featb, wt1, bias1, h1,
                                                     nullptr, nullptr, nullptr);
  } else {
    prep_all<<<3112, 256, 0, stream>>>(nw1, sw1, nw2, sw2, nb1, sb1, nb2, sb2,
                                       nw3, sw3, wt1, wt2, bias1, bias2, w3cat,
                                       accN, feat, nullptr, 0);
    gemm1_k<true><<<(Msz / 128) * (Nsz / 128), 256, 0, stream>>>(feat, wt1, bias1, h1, Dsz);
  }
  gemm8_k<Hsz, Nsz, true><<<g8, 512, 0, stream>>>(h1, wt2, bias2, nullptr,
                                                  w3cat, accN, accS);
  finalize_scan<<<Bsz, 64, 0, stream>>>(accN, accS, nb3, sb3, voff, vscl, rew, cont,
                                        o_rew, o_ret, o_tar, o_cri, o_slo);
}